// Round 1
// baseline (44.007 us; speedup 1.0000x reference)
//
#include <hip/hip_runtime.h>

// PlaylistEmbedding: out[b, :] = sum_n values[b,n] * w[indices[b,n], :] + bias
// B=16384, NNZ=200, EMB=32, all fp32 (indices int32).
//
// Layout: 256 threads/block. tid = r*8 + c:
//   c in [0,8)  -> which float4 chunk of the 32-wide embedding
//   r in [0,32) -> local output row
// Grid = 16384/32 = 512 blocks.
// Indices+values for the block's 32 rows staged in LDS (coalesced global
// loads), then the compute loop does broadcast LDS reads + float4 gathers
// from w (each w row = exactly one 128B cache line).

constexpr int NNZ = 200;
constexpr int ROWS_PER_BLOCK = 32;
constexpr int THREADS = 256;

__global__ __launch_bounds__(THREADS) void playlist_embedding_kernel(
    const int* __restrict__ indices,     // [B, NNZ]
    const float* __restrict__ values,    // [B, NNZ]
    const float* __restrict__ w,         // [VOCAB, 32]
    const float* __restrict__ bias,      // [32]
    float* __restrict__ out)             // [B, 32]
{
    __shared__ int   s_idx[ROWS_PER_BLOCK * NNZ];
    __shared__ float s_val[ROWS_PER_BLOCK * NNZ];

    const int tid = threadIdx.x;
    const int block_row0 = blockIdx.x * ROWS_PER_BLOCK;

    // --- Stage indices + values for 32 rows (6400 each), fully coalesced ---
    const int total = ROWS_PER_BLOCK * NNZ;              // 6400
    const int* __restrict__ g_idx = indices + (size_t)block_row0 * NNZ;
    const float* __restrict__ g_val = values + (size_t)block_row0 * NNZ;
    #pragma unroll
    for (int i = tid; i < total; i += THREADS) {         // 25 iters
        s_idx[i] = g_idx[i];
        s_val[i] = g_val[i];
    }
    __syncthreads();

    // --- Compute ---
    const int c = tid & 7;    // float4 chunk of EMB
    const int r = tid >> 3;   // local row

    const float4* __restrict__ w4 = (const float4*)w;
    const float4 bias4 = ((const float4*)bias)[c];

    const int*   __restrict__ row_idx = s_idx + r * NNZ;
    const float* __restrict__ row_val = s_val + r * NNZ;

    float ax = 0.f, ay = 0.f, az = 0.f, aw = 0.f;
    #pragma unroll 8
    for (int n = 0; n < NNZ; ++n) {                      // 200 = 25*8
        const int u = row_idx[n];                        // broadcast within 8-lane group
        const float v = row_val[n];
        const float4 wv = w4[u * 8 + c];                 // 16B of a 128B line
        ax += v * wv.x;
        ay += v * wv.y;
        az += v * wv.z;
        aw += v * wv.w;
    }

    float4 o;
    o.x = ax + bias4.x;
    o.y = ay + bias4.y;
    o.z = az + bias4.z;
    o.w = aw + bias4.w;
    ((float4*)out)[(size_t)(block_row0 + r) * 8 + c] = o;
}

extern "C" void kernel_launch(void* const* d_in, const int* in_sizes, int n_in,
                              void* d_out, int out_size, void* d_ws, size_t ws_size,
                              hipStream_t stream) {
    const int*   indices = (const int*)d_in[0];    // [16384, 200]
    const float* values  = (const float*)d_in[1];  // [16384, 200]
    const float* w       = (const float*)d_in[2];  // [81616, 32]
    const float* bias    = (const float*)d_in[3];  // [32]
    float* out = (float*)d_out;                    // [16384, 32]

    const int B = in_sizes[0] / NNZ;               // 16384
    const int grid = B / ROWS_PER_BLOCK;           // 512

    playlist_embedding_kernel<<<grid, THREADS, 0, stream>>>(
        indices, values, w, bias, out);
}